// Round 1
// baseline (1151.202 us; speedup 1.0000x reference)
//
#include <hip/hip_runtime.h>

#define T_STEPS 1024
#define BATCH 128

using u16 = unsigned short;

__device__ __forceinline__ float bf2f(u16 u) {
  union { unsigned int i; float f; } c; c.i = ((unsigned int)u) << 16; return c.f;
}

// x [B,64,T] f32 (binary) -> S0 [(b*T+t), 64] bf16-as-u16 (exact for 0/1)
__global__ __launch_bounds__(256) void k_transpose(const float* __restrict__ x,
                                                   u16* __restrict__ s0) {
  __shared__ float tile[64][65];
  const int b = blockIdx.y, t0 = blockIdx.x * 64, tid = threadIdx.x;
  {
    const int tt = tid & 63, ic = tid >> 6;  // ic in 0..3
#pragma unroll
    for (int ii = 0; ii < 16; ++ii) {
      const int i = ic * 16 + ii;
      tile[i][tt] = x[((size_t)b * 64 + i) * T_STEPS + t0 + tt];
    }
  }
  __syncthreads();
  {
    const int i = tid & 63, tc = tid >> 6;
#pragma unroll
    for (int jj = 0; jj < 16; ++jj) {
      const int t = tc * 16 + jj;
      const float v = tile[i][t];
      s0[((size_t)b * T_STEPS + t0 + t) * 64 + i] = (u16)(__float_as_uint(v) >> 16);
    }
  }
}

// Z[m, o0+0..63] = 2 * sum_k S[m,k]*W[o,k]; S: [M,K] bf16(u16), W: [NOUT,K] f32.
// grid = (M/64, NOUT/64), block = 256. Each thread: 4x4 micro-tile.
template <int K>
__global__ __launch_bounds__(256) void k_gemm(const u16* __restrict__ S,
                                              const float* __restrict__ W,
                                              float* __restrict__ Z, int nstride) {
  __shared__ float sA[16][66];  // [k][m]
  __shared__ float sB[16][66];  // [k][o]
  const int m0 = blockIdx.x * 64, o0 = blockIdx.y * 64;
  const int tid = threadIdx.x;
  const int tx = tid & 15, ty = tid >> 4;
  const int lr = tid >> 2;        // 0..63
  const int lk = (tid & 3) * 4;   // 0,4,8,12
  float acc[4][4] = {};
  for (int kk = 0; kk < K; kk += 16) {
    const ushort4 av = *reinterpret_cast<const ushort4*>(S + (size_t)(m0 + lr) * K + kk + lk);
    const float4 bv = *reinterpret_cast<const float4*>(W + (size_t)(o0 + lr) * K + kk + lk);
    __syncthreads();  // guard previous iteration's reads
    sA[lk + 0][lr] = bf2f(av.x);
    sA[lk + 1][lr] = bf2f(av.y);
    sA[lk + 2][lr] = bf2f(av.z);
    sA[lk + 3][lr] = bf2f(av.w);
    sB[lk + 0][lr] = bv.x;
    sB[lk + 1][lr] = bv.y;
    sB[lk + 2][lr] = bv.z;
    sB[lk + 3][lr] = bv.w;
    __syncthreads();
#pragma unroll
    for (int k = 0; k < 16; ++k) {
      float a[4], bb[4];
#pragma unroll
      for (int i = 0; i < 4; ++i) a[i] = sA[k][ty * 4 + i];
#pragma unroll
      for (int j = 0; j < 4; ++j) bb[j] = sB[k][tx * 4 + j];
#pragma unroll
      for (int i = 0; i < 4; ++i)
#pragma unroll
        for (int j = 0; j < 4; ++j) acc[i][j] += a[i] * bb[j];
    }
  }
#pragma unroll
  for (int i = 0; i < 4; ++i) {
    float4 o;
    o.x = 2.f * acc[i][0];
    o.y = 2.f * acc[i][1];
    o.z = 2.f * acc[i][2];
    o.w = 2.f * acc[i][3];
    *reinterpret_cast<float4*>(Z + (size_t)(m0 + ty * 4 + i) * nstride + o0 + tx * 4) = o;
  }
}

// Layer-3 GEMM: Z3[m, o<11] = 2 * sum_k S[m,k]*W3[o,k], Z3 stride 16.
__global__ __launch_bounds__(256) void k_gemm_out(const u16* __restrict__ S,
                                                  const float* __restrict__ W3,
                                                  float* __restrict__ Z3) {
  __shared__ u16 sS[64 * 264];  // rows padded to 264 (16B-aligned, fewer bank conflicts)
  const int m0 = blockIdx.x * 64;
  const int tid = threadIdx.x;
#pragma unroll
  for (int c = 0; c < 8; ++c) {
    const int e = (c * 256 + tid) * 8;
    const int r = e >> 8, k = e & 255;
    *reinterpret_cast<uint4*>(&sS[r * 264 + k]) =
        *reinterpret_cast<const uint4*>(S + (size_t)(m0 + r) * 256 + k);
  }
  __syncthreads();
  const int ml = tid & 63, og = tid >> 6;
  const u16* row = &sS[ml * 264];
  for (int o = og; o < 11; o += 4) {
    float acc = 0.f;
    const float* w = W3 + o * 256;
    for (int k = 0; k < 256; ++k) acc += bf2f(row[k]) * w[k];
    Z3[(size_t)(m0 + ml) * 16 + o] = 2.f * acc;
  }
}

// LIF scan with fused axonal delay: Sout[t+d] = spike(t); Sout[t<d] = 0.
__global__ __launch_bounds__(256) void k_scan_delay(const float* __restrict__ Z,
                                                    u16* __restrict__ Sout,
                                                    const int* __restrict__ d) {
  const int b = blockIdx.x, n = threadIdx.x;
  const int del = d[n];
  const float* zp = Z + (size_t)b * T_STEPS * 256 + n;
  u16* sp = Sout + (size_t)b * T_STEPS * 256 + n;
  for (int t = 0; t < del; ++t) sp[(size_t)t * 256] = 0;
  float cur = 0.f, vol = 0.f;
  const int tmax = T_STEPS - del;
#pragma unroll 4
  for (int t = 0; t < T_STEPS; ++t) {
    const float z = zp[(size_t)t * 256];
    cur = 0.75f * cur + z;
    vol = 0.75f * vol + cur;
    const bool s = (vol >= 1.25f);
    vol = s ? 0.f : vol;
    if (t < tmax) sp[(size_t)(t + del) * 256] = s ? (u16)0x3F80 : (u16)0;
  }
}

// Final LIF scan, no delay, writes out[b,o,t] f32.
__global__ void k_scan_out(const float* __restrict__ Z3, float* __restrict__ out) {
  const int id = blockIdx.x * blockDim.x + threadIdx.x;
  if (id >= BATCH * 11) return;
  const int b = id / 11, o = id % 11;
  const float* zp = Z3 + (size_t)b * T_STEPS * 16 + o;
  float* op = out + ((size_t)b * 11 + o) * T_STEPS;
  float cur = 0.f, vol = 0.f;
#pragma unroll 4
  for (int t = 0; t < T_STEPS; ++t) {
    const float z = zp[(size_t)t * 16];
    cur = 0.75f * cur + z;
    vol = 0.75f * vol + cur;
    const bool s = (vol >= 1.25f);
    vol = s ? 0.f : vol;
    op[t] = s ? 1.f : 0.f;
  }
}

extern "C" void kernel_launch(void* const* d_in, const int* in_sizes, int n_in,
                              void* d_out, int out_size, void* d_ws, size_t ws_size,
                              hipStream_t stream) {
  const float* x = (const float*)d_in[0];
  const float* w1 = (const float*)d_in[1];
  const float* w2 = (const float*)d_in[2];
  const float* w3 = (const float*)d_in[3];
  const int* d1 = (const int*)d_in[4];
  const int* d2 = (const int*)d_in[5];
  float* out = (float*)d_out;

  const int M = BATCH * T_STEPS;  // 131072
  float* Z = (float*)d_ws;                                  // [M,256] f32 = 134 MB
  u16* Sb = (u16*)((char*)d_ws + (size_t)M * 256 * 4);      // [M,256] u16 = 67 MB

  // 1. x -> S0 [M,64]
  k_transpose<<<dim3(T_STEPS / 64, BATCH), 256, 0, stream>>>(x, Sb);
  // 2. Z1 = 2 * S0 @ W1^T  [M,256]
  k_gemm<64><<<dim3(M / 64, 4), 256, 0, stream>>>(Sb, w1, Z, 256);
  // 3. LIF scan + delay d1 -> S1 [M,256]
  k_scan_delay<<<BATCH, 256, 0, stream>>>(Z, Sb, d1);
  // 4. Z2 = 2 * S1 @ W2^T  [M,256]
  k_gemm<256><<<dim3(M / 64, 4), 256, 0, stream>>>(Sb, w2, Z, 256);
  // 5. LIF scan + delay d2 -> S2 [M,256]
  k_scan_delay<<<BATCH, 256, 0, stream>>>(Z, Sb, d2);
  // 6. Z3 = 2 * S2 @ W3^T  [M,16(11 used)]
  k_gemm_out<<<M / 64, 256, 0, stream>>>(Sb, w3, Z);
  // 7. LIF scan -> out [B,11,T]
  k_scan_out<<<(BATCH * 11 + 255) / 256, 256, 0, stream>>>(Z, out);
}

// Round 2
// 527.658 us; speedup vs baseline: 2.1817x; 2.1817x over previous
//
#include <hip/hip_runtime.h>

#define T_STEPS 1024
#define BATCH 128

using u16 = unsigned short;

__device__ __forceinline__ float bf2f(u16 u) {
  union { unsigned int i; float f; } c; c.i = ((unsigned int)u) << 16; return c.f;
}

// x [B,64,T] f32 (binary) -> S0 [(b*T+t), 64] bf16-as-u16 (exact for 0/1)
__global__ __launch_bounds__(256) void k_transpose(const float* __restrict__ x,
                                                   u16* __restrict__ s0) {
  __shared__ float tile[64][65];
  const int b = blockIdx.y, t0 = blockIdx.x * 64, tid = threadIdx.x;
  {
    const int tt = tid & 63, ic = tid >> 6;  // ic in 0..3
#pragma unroll
    for (int ii = 0; ii < 16; ++ii) {
      const int i = ic * 16 + ii;
      tile[i][tt] = x[((size_t)b * 64 + i) * T_STEPS + t0 + tt];
    }
  }
  __syncthreads();
  {
    const int i = tid & 63, tc = tid >> 6;
#pragma unroll
    for (int jj = 0; jj < 16; ++jj) {
      const int t = tc * 16 + jj;
      const float v = tile[i][t];
      s0[((size_t)b * T_STEPS + t0 + t) * 64 + i] = (u16)(__float_as_uint(v) >> 16);
    }
  }
}

// Z[m, o0+0..63] = 2 * sum_k S[m,k]*W[o,k]; S: [M,K] bf16(u16), W: [NOUT,K] f32.
// grid = (M/64, NOUT/64), block = 256. Each thread: 4x4 micro-tile.
template <int K>
__global__ __launch_bounds__(256) void k_gemm(const u16* __restrict__ S,
                                              const float* __restrict__ W,
                                              float* __restrict__ Z, int nstride) {
  __shared__ float sA[16][66];  // [k][m]
  __shared__ float sB[16][66];  // [k][o]
  const int m0 = blockIdx.x * 64, o0 = blockIdx.y * 64;
  const int tid = threadIdx.x;
  const int tx = tid & 15, ty = tid >> 4;
  const int lr = tid >> 2;        // 0..63
  const int lk = (tid & 3) * 4;   // 0,4,8,12
  float acc[4][4] = {};
  for (int kk = 0; kk < K; kk += 16) {
    const ushort4 av = *reinterpret_cast<const ushort4*>(S + (size_t)(m0 + lr) * K + kk + lk);
    const float4 bv = *reinterpret_cast<const float4*>(W + (size_t)(o0 + lr) * K + kk + lk);
    __syncthreads();  // guard previous iteration's reads
    sA[lk + 0][lr] = bf2f(av.x);
    sA[lk + 1][lr] = bf2f(av.y);
    sA[lk + 2][lr] = bf2f(av.z);
    sA[lk + 3][lr] = bf2f(av.w);
    sB[lk + 0][lr] = bv.x;
    sB[lk + 1][lr] = bv.y;
    sB[lk + 2][lr] = bv.z;
    sB[lk + 3][lr] = bv.w;
    __syncthreads();
#pragma unroll
    for (int k = 0; k < 16; ++k) {
      float a[4], bb[4];
#pragma unroll
      for (int i = 0; i < 4; ++i) a[i] = sA[k][ty * 4 + i];
#pragma unroll
      for (int j = 0; j < 4; ++j) bb[j] = sB[k][tx * 4 + j];
#pragma unroll
      for (int i = 0; i < 4; ++i)
#pragma unroll
        for (int j = 0; j < 4; ++j) acc[i][j] += a[i] * bb[j];
    }
  }
#pragma unroll
  for (int i = 0; i < 4; ++i) {
    float4 o;
    o.x = 2.f * acc[i][0];
    o.y = 2.f * acc[i][1];
    o.z = 2.f * acc[i][2];
    o.w = 2.f * acc[i][3];
    *reinterpret_cast<float4*>(Z + (size_t)(m0 + ty * 4 + i) * nstride + o0 + tx * 4) = o;
  }
}

// Layer-3 GEMM: Z3[m, o<11] = 2 * sum_k S[m,k]*W3[o,k], Z3 stride 16.
__global__ __launch_bounds__(256) void k_gemm_out(const u16* __restrict__ S,
                                                  const float* __restrict__ W3,
                                                  float* __restrict__ Z3) {
  __shared__ u16 sS[64 * 264];  // rows padded to 264 (16B-aligned, fewer bank conflicts)
  const int m0 = blockIdx.x * 64;
  const int tid = threadIdx.x;
#pragma unroll
  for (int c = 0; c < 8; ++c) {
    const int e = (c * 256 + tid) * 8;
    const int r = e >> 8, k = e & 255;
    *reinterpret_cast<uint4*>(&sS[r * 264 + k]) =
        *reinterpret_cast<const uint4*>(S + (size_t)(m0 + r) * 256 + k);
  }
  __syncthreads();
  const int ml = tid & 63, og = tid >> 6;
  const u16* row = &sS[ml * 264];
  for (int o = og; o < 11; o += 4) {
    float acc = 0.f;
    const float* w = W3 + o * 256;
    for (int k = 0; k < 256; ++k) acc += bf2f(row[k]) * w[k];
    Z3[(size_t)(m0 + ml) * 16 + o] = 2.f * acc;
  }
}

// ---- deep-prefetch helpers (all indices compile-time after unroll; rule #20) ----
template <int CH, int STR>
__device__ __forceinline__ void load_chunk(const float* __restrict__ zp, int base,
                                           float (&zb)[CH]) {
#pragma unroll
  for (int u = 0; u < CH; ++u) zb[u] = zp[(size_t)(base + u) * STR];
}

// LIF scan with fused axonal delay: Sout[t+d] = spike(t); Sout[t<d] = 0.
// grid = 256 (b, n-half), block = 128. Two 32-deep register buffers ping-pong
// (named arrays -> static indexing -> no scratch) so ~32 loads stay in flight.
__global__ __launch_bounds__(128) void k_scan_delay(const float* __restrict__ Z,
                                                    u16* __restrict__ Sout,
                                                    const int* __restrict__ d) {
  const int b = blockIdx.x >> 1, nh = blockIdx.x & 1;
  const int n = (nh << 7) + threadIdx.x;
  const int del = d[n];
  const float* zp = Z + (size_t)b * T_STEPS * 256 + n;
  u16* sp = Sout + (size_t)b * T_STEPS * 256 + n;
  for (int t = 0; t < del; ++t) sp[(size_t)t * 256] = 0;
  const int tmax = T_STEPS - del;
  float cur = 0.f, vol = 0.f;
  float zA[32], zB[32];
  load_chunk<32, 256>(zp, 0, zA);
  for (int c = 0; c < 32; c += 2) {
    if (c + 1 < 32) load_chunk<32, 256>(zp, (c + 1) * 32, zB);
#pragma unroll
    for (int u = 0; u < 32; ++u) {
      const int t = c * 32 + u;
      cur = 0.75f * cur + zA[u];
      vol = 0.75f * vol + cur;
      const bool s = vol >= 1.25f;
      vol = s ? 0.f : vol;
      if (t < tmax) sp[(size_t)(t + del) * 256] = s ? (u16)0x3F80 : (u16)0;
    }
    if (c + 2 < 32) load_chunk<32, 256>(zp, (c + 2) * 32, zA);
#pragma unroll
    for (int u = 0; u < 32; ++u) {
      const int t = (c + 1) * 32 + u;
      cur = 0.75f * cur + zB[u];
      vol = 0.75f * vol + cur;
      const bool s = vol >= 1.25f;
      vol = s ? 0.f : vol;
      if (t < tmax) sp[(size_t)(t + del) * 256] = s ? (u16)0x3F80 : (u16)0;
    }
  }
}

// Final LIF scan, no delay, writes out[b,o,t] f32. grid = B, block = 64 (11 active).
__global__ __launch_bounds__(64) void k_scan_out(const float* __restrict__ Z3,
                                                 float* __restrict__ out) {
  const int b = blockIdx.x, o = threadIdx.x;
  if (o >= 11) return;
  const float* zp = Z3 + (size_t)b * T_STEPS * 16 + o;
  float* op = out + ((size_t)b * 11 + o) * T_STEPS;
  float cur = 0.f, vol = 0.f;
  float zA[32], zB[32], ob[4];
  load_chunk<32, 16>(zp, 0, zA);
  for (int c = 0; c < 32; c += 2) {
    if (c + 1 < 32) load_chunk<32, 16>(zp, (c + 1) * 32, zB);
#pragma unroll
    for (int u = 0; u < 32; ++u) {
      cur = 0.75f * cur + zA[u];
      vol = 0.75f * vol + cur;
      const bool s = vol >= 1.25f;
      vol = s ? 0.f : vol;
      ob[u & 3] = s ? 1.f : 0.f;
      if ((u & 3) == 3)
        *reinterpret_cast<float4*>(op + c * 32 + (u - 3)) =
            make_float4(ob[0], ob[1], ob[2], ob[3]);
    }
    if (c + 2 < 32) load_chunk<32, 16>(zp, (c + 2) * 32, zA);
#pragma unroll
    for (int u = 0; u < 32; ++u) {
      cur = 0.75f * cur + zB[u];
      vol = 0.75f * vol + cur;
      const bool s = vol >= 1.25f;
      vol = s ? 0.f : vol;
      ob[u & 3] = s ? 1.f : 0.f;
      if ((u & 3) == 3)
        *reinterpret_cast<float4*>(op + (c + 1) * 32 + (u - 3)) =
            make_float4(ob[0], ob[1], ob[2], ob[3]);
    }
  }
}

extern "C" void kernel_launch(void* const* d_in, const int* in_sizes, int n_in,
                              void* d_out, int out_size, void* d_ws, size_t ws_size,
                              hipStream_t stream) {
  const float* x = (const float*)d_in[0];
  const float* w1 = (const float*)d_in[1];
  const float* w2 = (const float*)d_in[2];
  const float* w3 = (const float*)d_in[3];
  const int* d1 = (const int*)d_in[4];
  const int* d2 = (const int*)d_in[5];
  float* out = (float*)d_out;

  const int M = BATCH * T_STEPS;  // 131072
  float* Z = (float*)d_ws;                                  // [M,256] f32 = 134 MB
  u16* Sb = (u16*)((char*)d_ws + (size_t)M * 256 * 4);      // [M,256] u16 = 67 MB

  // 1. x -> S0 [M,64]
  k_transpose<<<dim3(T_STEPS / 64, BATCH), 256, 0, stream>>>(x, Sb);
  // 2. Z1 = 2 * S0 @ W1^T  [M,256]
  k_gemm<64><<<dim3(M / 64, 4), 256, 0, stream>>>(Sb, w1, Z, 256);
  // 3. LIF scan + delay d1 -> S1 [M,256]
  k_scan_delay<<<BATCH * 2, 128, 0, stream>>>(Z, Sb, d1);
  // 4. Z2 = 2 * S1 @ W2^T  [M,256]
  k_gemm<256><<<dim3(M / 64, 4), 256, 0, stream>>>(Sb, w2, Z, 256);
  // 5. LIF scan + delay d2 -> S2 [M,256]
  k_scan_delay<<<BATCH * 2, 128, 0, stream>>>(Z, Sb, d2);
  // 6. Z3 = 2 * S2 @ W3^T  [M,16(11 used)]
  k_gemm_out<<<M / 64, 256, 0, stream>>>(Sb, w3, Z);
  // 7. LIF scan -> out [B,11,T]
  k_scan_out<<<BATCH, 64, 0, stream>>>(Z, out);
}